// Round 2
// baseline (960.770 us; speedup 1.0000x reference)
//
#include <hip/hip_runtime.h>
#include <hip/hip_bf16.h>

#define RNUM 8
#define HH1 32
#define HH2 16
#define FIN 128
#define NPB 16
#define SCAN_T 1024

// --- histogram of (dst, rel) ---
__global__ __launch_bounds__(256) void k_count(const int* __restrict__ ei,
    const int* __restrict__ ea, int* __restrict__ cnt8, int E) {
  int e = blockIdx.x * 256 + threadIdx.x;
  if (e < E) {
    atomicAdd(&cnt8[ei[E + e] * RNUM + ea[e]], 1);
  }
}

// --- per-dst totals + 1/max(cnt,1) ---
__global__ __launch_bounds__(256) void k_prep(const int* __restrict__ cnt8,
    float* __restrict__ invc, int* __restrict__ cntd, int N) {
  int d = blockIdx.x * 256 + threadIdx.x;
  if (d < N) {
    int s = 0;
    #pragma unroll
    for (int r = 0; r < RNUM; ++r) {
      int c = cnt8[d * RNUM + r];
      s += c;
      invc[d * RNUM + r] = 1.0f / (float)(c > 1 ? c : 1);
    }
    cntd[d] = s;
  }
}

// --- single-block exclusive scan over N dst counts -> rowptr[N+1] ---
__global__ __launch_bounds__(SCAN_T) void k_scan(const int* __restrict__ cntd,
    int* __restrict__ rowptr, int N) {
  __shared__ int part[SCAN_T];
  int t = threadIdx.x;
  int ipt = (N + SCAN_T - 1) / SCAN_T;
  int lo = t * ipt, hi = min(N, lo + ipt);
  int s = 0;
  for (int i = lo; i < hi; ++i) s += cntd[i];
  part[t] = s;
  __syncthreads();
  for (int d = 1; d < SCAN_T; d <<= 1) {
    int v = (t >= d) ? part[t - d] : 0;
    __syncthreads();
    part[t] += v;
    __syncthreads();
  }
  int run = (t == 0) ? 0 : part[t - 1];
  for (int i = lo; i < hi; ++i) { rowptr[i] = run; run += cntd[i]; }
  if (t == SCAN_T - 1) rowptr[N] = run;
}

// --- scatter edges into dst-sorted order; payload = xw row index (src*8+rel) ---
__global__ __launch_bounds__(256) void k_scatter(const int* __restrict__ ei,
    const int* __restrict__ ea, const int* __restrict__ rowptr,
    int* __restrict__ ofs, unsigned* __restrict__ perm, int E) {
  int e = blockIdx.x * 256 + threadIdx.x;
  if (e < E) {
    int src = ei[e], dst = ei[E + e], rel = ea[e];
    int pos = rowptr[dst] + atomicAdd(&ofs[dst], 1);
    perm[pos] = ((unsigned)src << 3) | (unsigned)rel;
  }
}

// xw1[n][r*32+h] (bf16) = x@W1 ; agg1[n][h] = x@root1 + b1
__global__ __launch_bounds__(256) void k_gemm1(const float* __restrict__ x,
    const float* __restrict__ W, const float* __restrict__ root,
    const float* __restrict__ b, __hip_bfloat16* __restrict__ xw,
    float* __restrict__ agg, int N) {
  __shared__ float xs[NPB][FIN];
  int n0 = blockIdx.x * NPB;
  int t = threadIdx.x;
  #pragma unroll
  for (int rep = 0; rep < 2; ++rep) {
    int q = t + rep * 256;
    int n = q >> 5;
    int i0 = (q & 31) << 2;
    int nn = n0 + n;
    float4 v = make_float4(0.f, 0.f, 0.f, 0.f);
    if (nn < N) v = *(const float4*)(x + (size_t)nn * FIN + i0);
    *(float4*)(&xs[n][i0]) = v;
  }
  __syncthreads();

  float acc[NPB];
  #pragma unroll
  for (int n = 0; n < NPB; ++n) acc[n] = 0.f;
  const float* Wc = W + ((t >> 5) * FIN * HH1) + (t & 31);
  #pragma unroll 4
  for (int i = 0; i < FIN; ++i) {
    float w = Wc[(size_t)i * HH1];
    #pragma unroll
    for (int n = 0; n < NPB; ++n) acc[n] = fmaf(w, xs[n][i], acc[n]);
  }
  #pragma unroll
  for (int n = 0; n < NPB; ++n) {
    int nn = n0 + n;
    if (nn < N) xw[(size_t)nn * (RNUM * HH1) + t] = __float2bfloat16(acc[n]);
  }

  int c = t & 31;
  int nr = t >> 5;
  float r0 = 0.f, r1 = 0.f;
  const float* Rc = root + c;
  #pragma unroll 4
  for (int i = 0; i < FIN; ++i) {
    float w = Rc[(size_t)i * HH1];
    r0 = fmaf(w, xs[nr][i], r0);
    r1 = fmaf(w, xs[nr + 8][i], r1);
  }
  float bb = b[c];
  int nn0 = n0 + nr, nn1 = n0 + nr + 8;
  if (nn0 < N) agg[(size_t)nn0 * HH1 + c] = r0 + bb;
  if (nn1 < N) agg[(size_t)nn1 * HH1 + c] = r1 + bb;
}

// one wave per dst: agg1[dst] += sum over sorted edges of invc * xw1[src,rel]
__global__ __launch_bounds__(256) void k_agg1(const int* __restrict__ rowptr,
    const unsigned* __restrict__ perm, const float* __restrict__ invc,
    const __hip_bfloat16* __restrict__ xw, float* __restrict__ agg, int N) {
  int wid = (blockIdx.x * 256 + threadIdx.x) >> 6;
  if (wid >= N) return;
  int lid = threadIdx.x & 63;
  int h = lid & 31, p = lid >> 5;
  int start = rowptr[wid], end = rowptr[wid + 1];
  float acc = 0.f;
  for (int e = start + p; e < end; e += 2) {
    unsigned idx = perm[e];
    float w = invc[(wid << 3) | (idx & 7u)];
    acc = fmaf(w, __bfloat162float(xw[(size_t)idx * HH1 + h]), acc);
  }
  acc += __shfl_xor(acc, 32);
  if (p == 0) {
    size_t o = (size_t)wid * HH1 + h;
    agg[o] += acc;
  }
}

// reads relu(agg1); xw2 (bf16) = h1@W2 ; agg2 = h1@root2 + b2
__global__ __launch_bounds__(256) void k_gemm2(const float* __restrict__ agg1,
    const float* __restrict__ W, const float* __restrict__ root,
    const float* __restrict__ b, __hip_bfloat16* __restrict__ xw,
    float* __restrict__ agg, int N) {
  __shared__ float hs[NPB][HH1];
  int n0 = blockIdx.x * NPB;
  int t = threadIdx.x;
  {
    int n = t >> 4;
    int i0 = (t & 15) << 1;
    int nn = n0 + n;
    float2 v = make_float2(0.f, 0.f);
    if (nn < N) v = *(const float2*)(agg1 + (size_t)nn * HH1 + i0);
    hs[n][i0] = fmaxf(v.x, 0.f);
    hs[n][i0 + 1] = fmaxf(v.y, 0.f);
  }
  __syncthreads();

  int c = t & 127;
  int ns = t >> 7;
  const float* Wc = W + ((c >> 4) * HH1 * HH2) + (c & 15);
  float acc[8];
  #pragma unroll
  for (int k = 0; k < 8; ++k) acc[k] = 0.f;
  #pragma unroll 4
  for (int i = 0; i < HH1; ++i) {
    float w = Wc[(size_t)i * HH2];
    #pragma unroll
    for (int k = 0; k < 8; ++k) acc[k] = fmaf(w, hs[ns + 2 * k][i], acc[k]);
  }
  #pragma unroll
  for (int k = 0; k < 8; ++k) {
    int nn = n0 + ns + 2 * k;
    if (nn < N) xw[(size_t)nn * (RNUM * HH2) + c] = __float2bfloat16(acc[k]);
  }

  int c2 = t & 15;
  int n = t >> 4;
  float r0 = 0.f;
  const float* Rc = root + c2;
  #pragma unroll 4
  for (int i = 0; i < HH1; ++i) r0 = fmaf(Rc[(size_t)i * HH2], hs[n][i], r0);
  int nn = n0 + n;
  if (nn < N) agg[(size_t)nn * HH2 + c2] = r0 + b[c2];
}

__global__ __launch_bounds__(256) void k_agg2(const int* __restrict__ rowptr,
    const unsigned* __restrict__ perm, const float* __restrict__ invc,
    const __hip_bfloat16* __restrict__ xw, float* __restrict__ agg, int N) {
  int wid = (blockIdx.x * 256 + threadIdx.x) >> 6;
  if (wid >= N) return;
  int lid = threadIdx.x & 63;
  int h = lid & 15, p = lid >> 4;
  int start = rowptr[wid], end = rowptr[wid + 1];
  float acc = 0.f;
  for (int e = start + p; e < end; e += 4) {
    unsigned idx = perm[e];
    float w = invc[(wid << 3) | (idx & 7u)];
    acc = fmaf(w, __bfloat162float(xw[(size_t)idx * HH2 + h]), acc);
  }
  acc += __shfl_xor(acc, 32);
  acc += __shfl_xor(acc, 16);
  if (p == 0) {
    size_t o = (size_t)wid * HH2 + h;
    agg[o] += acc;
  }
}

__global__ __launch_bounds__(256) void k_pool(const float* __restrict__ agg2,
    const int* __restrict__ batch, unsigned* __restrict__ pooled, int N) {
  int gid = blockIdx.x * 256 + threadIdx.x;
  int n = gid >> 4;
  if (n < N) {
    int h = gid & 15;
    float v = fmaxf(agg2[(size_t)n * HH2 + h], 0.f);
    atomicMax(&pooled[batch[n] * HH2 + h], __float_as_uint(v));
  }
}

__global__ __launch_bounds__(256) void k_dense(const float* __restrict__ pooled,
    const float* __restrict__ dw, const float* __restrict__ db,
    float* __restrict__ out, int Gn) {
  int g = blockIdx.x * 256 + threadIdx.x;
  if (g < Gn) {
    float s = db[0];
    #pragma unroll
    for (int h = 0; h < HH2; ++h) s += pooled[(size_t)g * HH2 + h] * dw[h];
    out[g] = s;
  }
}

extern "C" void kernel_launch(void* const* d_in, const int* in_sizes, int n_in,
                              void* d_out, int out_size, void* d_ws, size_t ws_size,
                              hipStream_t stream) {
  const float* x     = (const float*)d_in[0];
  const int*   ei    = (const int*)d_in[1];
  const int*   ea    = (const int*)d_in[2];
  const int*   batch = (const int*)d_in[3];
  const float* W1    = (const float*)d_in[4];
  const float* root1 = (const float*)d_in[5];
  const float* b1    = (const float*)d_in[6];
  const float* W2    = (const float*)d_in[7];
  const float* root2 = (const float*)d_in[8];
  const float* b2    = (const float*)d_in[9];
  const float* dw    = (const float*)d_in[10];
  const float* db    = (const float*)d_in[11];
  float* out = (float*)d_out;

  const int N  = in_sizes[0] / FIN;
  const int E  = in_sizes[2];
  const int Gn = out_size;

  char* ws = (char*)d_ws;
  size_t off = 0;
  auto walloc = [&](size_t bytes) -> void* {
    void* p = (void*)(ws + off);
    off += (bytes + 255) & ~(size_t)255;
    return p;
  };
  int*            cnt8   = (int*)            walloc((size_t)N * RNUM * 4);
  float*          invc   = (float*)          walloc((size_t)N * RNUM * 4);
  int*            cntd   = (int*)            walloc((size_t)N * 4);
  int*            rowptr = (int*)            walloc(((size_t)N + 1) * 4);
  int*            ofs    = (int*)            walloc((size_t)N * 4);
  unsigned*       perm   = (unsigned*)       walloc((size_t)E * 4);
  __hip_bfloat16* xw1    = (__hip_bfloat16*) walloc((size_t)N * RNUM * HH1 * 2);
  float*          agg1   = (float*)          walloc((size_t)N * HH1 * 4);
  __hip_bfloat16* xw2    = (__hip_bfloat16*) walloc((size_t)N * RNUM * HH2 * 2);
  float*          agg2   = (float*)          walloc((size_t)N * HH2 * 4);
  unsigned*       pooled = (unsigned*)       walloc((size_t)Gn * HH2 * 4);

  hipMemsetAsync(cnt8, 0, (size_t)N * RNUM * 4, stream);
  hipMemsetAsync(ofs, 0, (size_t)N * 4, stream);
  hipMemsetAsync(pooled, 0, (size_t)Gn * HH2 * 4, stream);

  k_count<<<(E + 255) / 256, 256, 0, stream>>>(ei, ea, cnt8, E);
  k_prep<<<(N + 255) / 256, 256, 0, stream>>>(cnt8, invc, cntd, N);
  k_scan<<<1, SCAN_T, 0, stream>>>(cntd, rowptr, N);
  k_scatter<<<(E + 255) / 256, 256, 0, stream>>>(ei, ea, rowptr, ofs, perm, E);

  k_gemm1<<<(N + NPB - 1) / NPB, 256, 0, stream>>>(x, W1, root1, b1, xw1, agg1, N);
  k_agg1<<<(int)(((long)N * 64 + 255) / 256), 256, 0, stream>>>(rowptr, perm, invc, xw1, agg1, N);
  k_gemm2<<<(N + NPB - 1) / NPB, 256, 0, stream>>>(agg1, W2, root2, b2, xw2, agg2, N);
  k_agg2<<<(int)(((long)N * 64 + 255) / 256), 256, 0, stream>>>(rowptr, perm, invc, xw2, agg2, N);
  k_pool<<<(int)(((long)N * HH2 + 255) / 256), 256, 0, stream>>>(agg2, batch, pooled, N);
  k_dense<<<(Gn + 255) / 256, 256, 0, stream>>>((const float*)pooled, dw, db, out, Gn);
}